// Round 6
// baseline (379.419 us; speedup 1.0000x reference)
//
#include <hip/hip_runtime.h>

typedef __bf16 bf16_t;
typedef __attribute__((ext_vector_type(8))) __bf16 bf16x8;
typedef __attribute__((ext_vector_type(4))) float f32x4;
typedef __attribute__((ext_vector_type(8))) unsigned short u16x8;

// async global->LDS DMA, 16B per lane; LDS dst must be linear in lane (base + lane*16)
__device__ __forceinline__ void dma16(const void* g, void* l) {
    __builtin_amdgcn_global_load_lds(
        reinterpret_cast<const unsigned int __attribute__((address_space(1)))*>(
            reinterpret_cast<unsigned long long>(g)),
        reinterpret_cast<unsigned int __attribute__((address_space(3)))*>(
            (unsigned int)reinterpret_cast<unsigned long long>(l)),
        16, 0, 0);
}

// ---------------- dtype detect: 1 = bf16 inputs, 0 = fp32 inputs.
__global__ void detect_dtype(const unsigned short* __restrict__ ct, int* __restrict__ flag) {
    if (threadIdx.x == 0 && blockIdx.x == 0) {
        int ok = 1;
        for (int i = 0; i < 16; i++) {
            int e = (ct[256 + i] >> 7) & 0xFF;
            ok &= (e >= 80 && e <= 126) ? 1 : 0;
        }
        *flag = ok;
    }
}

// ---------------- scan: wave-aggregated partition (1 atomic per wave per bucket)
__global__ void scan_rows(const int* __restrict__ lvl2, const int* __restrict__ lvl1,
                          const int* __restrict__ lvl0, const int* __restrict__ third,
                          int* __restrict__ lists, int* __restrict__ cnts, int* __restrict__ inv) {
    int r = blockIdx.x * 256 + threadIdx.x;   // grid covers exactly 28672
    int slot, lr, base_t, base_b;
    const int* lvl;
    if (r < 16384)      { slot = 0; lr = r;         lvl = lvl2; base_t = 0;     base_b = 16384; }
    else if (r < 24576) { slot = 1; lr = r - 16384; lvl = lvl1; base_t = 32768; base_b = 40960; }
    else                { slot = 2; lr = r - 24576; lvl = lvl0; base_t = 49152; base_b = 53248; }
    int node = lvl[lr];
    int tern = third[node] >= 0 ? 1 : 0;
    if (slot == 0)      inv[node] = lr;
    else if (slot == 1) inv[node] = 16384 + lr;

    unsigned long long bt = __ballot(tern);
    unsigned long long bb = __ballot(!tern);
    int lane = threadIdx.x & 63;
    unsigned long long ltm = (1ull << lane) - 1ull;
    int post = __popcll(bt & ltm), posb = __popcll(bb & ltm);
    int baseT = 0, baseB = 0;
    if (lane == 0) {
        baseT = atomicAdd(&cnts[slot * 2 + 1], __popcll(bt));
        baseB = atomicAdd(&cnts[slot * 2 + 0], __popcll(bb));
    }
    baseT = __shfl(baseT, 0, 64);
    baseB = __shfl(baseB, 0, 64);
    lists[tern ? (base_t + baseT + post) : (base_b + baseB + posb)] = lr;
}

// ---------------- pack weights [K][N] -> [kc][n][32] bf16 (DMA-staging friendly)
__device__ __forceinline__ void packw(const void* __restrict__ src, bf16_t* __restrict__ dst,
                                      int e, int Nmask, int Nshift, int isbf) {
    bf16_t v = isbf ? ((const bf16_t*)src)[e] : (bf16_t)((const float*)src)[e];
    int n = e & Nmask, k = e >> Nshift;
    dst[(size_t)((((k >> 5) << Nshift) + n) * 32 + (k & 31))] = v;
}

__global__ void pack_all(const void* __restrict__ W1t, const void* __restrict__ W1b,
                         const void* __restrict__ W2t, const void* __restrict__ W2b,
                         const void* __restrict__ op,
                         bf16_t* __restrict__ W1tf, bf16_t* __restrict__ W1bf,
                         bf16_t* __restrict__ W2tf, bf16_t* __restrict__ W2bf,
                         bf16_t* __restrict__ opb, const int* __restrict__ flagp) {
    int e = blockIdx.x * 256 + threadIdx.x;
    int isbf = *flagp;
    if (e < 524288)       packw(W1t, W1tf, e, 511, 9, isbf);
    else if (e < 917504)  packw(W1b, W1bf, e - 524288, 511, 9, isbf);
    else if (e < 1048576) packw(W2t, W2tf, e - 917504, 255, 8, isbf);
    else if (e < 1179648) packw(W2b, W2bf, e - 1048576, 255, 8, isbf);
    else if (e < 1183744) {
        int i = e - 1179648;   // 16*256 op_table -> bf16
        opb[i] = isbf ? ((const bf16_t*)op)[i] : (bf16_t)((const float*)op)[i];
    }
}

__device__ __forceinline__ float ldparam(const void* p, int i, int isbf) {
    return isbf ? (float)((const bf16_t*)p)[i] : ((const float*)p)[i];
}

// ---------------- GEMM1: [rows x K1] @ W1 -> GELU -> H   (BM=128, BN=128, BK=32)
__global__ __launch_bounds__(256, 3) void gemm1(
    const int* __restrict__ list_t, const int* __restrict__ list_b,
    const int* __restrict__ cntpair, const int* __restrict__ lvl_idx,
    const int* __restrict__ op_ids, const int* __restrict__ lch,
    const int* __restrict__ rch, const int* __restrict__ tch,
    const bf16_t* __restrict__ ne2, const bf16_t* __restrict__ opb,
    const void* __restrict__ ct, const int* __restrict__ cid,
    const int* __restrict__ inv, const int* __restrict__ flagp,
    const bf16_t* __restrict__ W1tf, const void* __restrict__ b1t,
    const bf16_t* __restrict__ W1bf, const void* __restrict__ b1b,
    bf16_t* __restrict__ H, int chunk)
{
    __shared__ __align__(16) unsigned short Ash[128 * 40]; // 10.24 KB, padded stride 40
    __shared__ __align__(16) unsigned short Bsh[128 * 32]; // 8 KB, DMA layout [n][32]

    const int tid = threadIdx.x;
    const int cnt_t = cntpair[1], cnt_b = cntpair[0];
    const int nbt = (cnt_t + 127) >> 7, nbb = (cnt_b + 127) >> 7;
    const int cbL = blockIdx.x >> 2, Nb = blockIdx.x & 3;
    const int cb = chunk * 65 + cbL;
    if (cb >= nbt + nbb) return;
    const int tern = cb < nbt;
    const int* list = tern ? list_t : list_b;
    const int base = (tern ? cb : cb - nbt) << 7;
    const int cnt = tern ? cnt_t : cnt_b;
    const int act = min(128, cnt - base);
    const int isbf = *flagp;
    const int K1c = tern ? 32 : 24;
    const bf16_t* W1f = tern ? W1tf : W1bf;
    const void* b1 = tern ? b1t : b1b;

    // staging identity: 2 threads per row, 16 shorts each
    const int r0 = tid >> 1, hh = tid & 1;
    const unsigned short* rowp[4]; int fm = 0;
    {
        int lr = list[base + min(r0, act - 1)];
        int nd = lvl_idx[lr];
        rowp[0] = (const unsigned short*)(opb + (size_t)op_ids[nd] * 256);
        int c0 = lch[nd], c1 = rch[nd], c2 = tern ? tch[nd] : c0;
        int chs[3] = {c0, c1, c2};
#pragma unroll
        for (int s = 0; s < 3; s++) {
            int iv = inv[chs[s]];
            if (iv >= 0) rowp[s + 1] = (const unsigned short*)(ne2 + (size_t)iv * 256);
            else if (isbf) rowp[s + 1] = (const unsigned short*)ct + (size_t)cid[chs[s]] * 256;
            else { rowp[s + 1] = (const unsigned short*)((const float*)ct + (size_t)cid[chs[s]] * 256);
                   fm |= 1 << (s + 1); }
        }
    }
    const int w = tid >> 6, lane = tid & 63, cc = lane & 15, qq = lane >> 4;
    const int wm = w >> 1, wn = w & 1;

    const f32x4 zf = {0.f, 0.f, 0.f, 0.f};
    f32x4 acc[4][4];
#pragma unroll
    for (int mi = 0; mi < 4; mi++) for (int ji = 0; ji < 4; ji++) acc[mi][ji] = zf;

    for (int kc = 0; kc < K1c; kc++) {
        __syncthreads();
        { // A gather (32 shorts per row, this thread: 16)
            int p = kc >> 3, off = (kc & 7) * 32 + hh * 16;
            unsigned short* dst = Ash + r0 * 40 + hh * 16;
            if (!((fm >> p) & 1)) {
                const unsigned short* sp = rowp[p] + off;
                *(u16x8*)dst = *(const u16x8*)sp;
                *(u16x8*)(dst + 8) = *(const u16x8*)(sp + 8);
            } else {
                const float* fp2 = (const float*)rowp[p] + off;
                bf16_t tmp[16];
#pragma unroll
                for (int z = 0; z < 16; z += 4) {
                    f32x4 fv = *(const f32x4*)(fp2 + z);
                    for (int y = 0; y < 4; y++) tmp[z + y] = (bf16_t)fv[y];
                }
                *(u16x8*)dst = *(const u16x8*)tmp;
                *(u16x8*)(dst + 8) = *(const u16x8*)(tmp + 8);
            }
            // B tile DMA: 8 KB
            const unsigned short* bs = (const unsigned short*)W1f + ((size_t)kc * 512 + Nb * 128) * 32;
            dma16(bs + tid * 8, Bsh + tid * 8);
            dma16(bs + 2048 + tid * 8, Bsh + 2048 + tid * 8);
        }
        __syncthreads();
        bf16x8 af[4];
#pragma unroll
        for (int mi = 0; mi < 4; mi++)
            af[mi] = *(const bf16x8*)((const bf16_t*)Ash + (wm * 64 + mi * 16 + cc) * 40 + qq * 8);
#pragma unroll
        for (int ji = 0; ji < 4; ji++) {
            bf16x8 bv = *(const bf16x8*)((const bf16_t*)Bsh + (wn * 64 + ji * 16 + cc) * 32 + qq * 8);
#pragma unroll
            for (int mi = 0; mi < 4; mi++)
                acc[mi][ji] = __builtin_amdgcn_mfma_f32_16x16x32_bf16(af[mi], bv, acc[mi][ji], 0, 0, 0);
        }
    }

    // epilogue: bias + exact GELU -> H
    const int hbase = cbL * 128;
#pragma unroll
    for (int ji = 0; ji < 4; ji++) {
        int colg = Nb * 128 + wn * 64 + ji * 16 + cc;
        float bb = ldparam(b1, colg, isbf);
#pragma unroll
        for (int mi = 0; mi < 4; mi++) for (int r = 0; r < 4; r++) {
            float v = acc[mi][ji][r] + bb;
            float h = 0.5f * v * (1.0f + erff(v * 0.70710678118654752f));
            H[(size_t)(hbase + wm * 64 + mi * 16 + qq * 4 + r) * 512 + colg] = (bf16_t)h;
        }
    }
}

// ---------------- GEMM2: H @ W2 + b2 + residual -> LN -> scatter (BM=64, BN=256)
__global__ __launch_bounds__(256, 2) void gemm2(
    const int* __restrict__ list_t, const int* __restrict__ list_b,
    const int* __restrict__ cntpair, const int* __restrict__ lvl_idx,
    const int* __restrict__ lch, const int* __restrict__ rch, const int* __restrict__ tch,
    bf16_t* __restrict__ ne2, const void* __restrict__ ct,
    const int* __restrict__ cid, const int* __restrict__ inv, const int* __restrict__ flagp,
    const bf16_t* __restrict__ W2tf, const void* __restrict__ b2t,
    const bf16_t* __restrict__ W2bf, const void* __restrict__ b2b,
    const void* __restrict__ gma, const void* __restrict__ bta,
    const bf16_t* __restrict__ H, int chunk, int slotBase, void* __restrict__ out)
{
    __shared__ __align__(16) char U[69888];
    unsigned short* Ash = (unsigned short*)U;           // [64][32] 4 KB  (phase 1)
    unsigned short* Bsh = (unsigned short*)(U + 4096);  // [256][32] 16 KB (phase 1)
    float* Rf    = (float*)U;                           // [64][260] 66.56 KB (phase 2)
    float* partS = (float*)(U + 66560);                 // [4][64]
    float* partQ = (float*)(U + 67584);                 // [4][64]
    float* muA   = (float*)(U + 68608);                 // [64]
    float* rsA   = (float*)(U + 68864);                 // [64]

    const int tid = threadIdx.x;
    const int cnt_t = cntpair[1], cnt_b = cntpair[0];
    const int nbt = (cnt_t + 127) >> 7, nbb = (cnt_b + 127) >> 7;
    const int cbL = blockIdx.x >> 1, half = blockIdx.x & 1;
    const int cb = chunk * 65 + cbL;
    if (cb >= nbt + nbb) return;
    const int tern = cb < nbt;
    const int* list = tern ? list_t : list_b;
    const int base = ((tern ? cb : cb - nbt) << 7) + (half << 6);
    const int cnt = tern ? cnt_t : cnt_b;
    if (base >= cnt) return;
    const int act = min(64, cnt - base);
    const int isbf = *flagp;
    const bf16_t* W2f = tern ? W2tf : W2bf;
    const void* b2 = tern ? b2t : b2b;
    const int hrow0 = cbL * 128 + half * 64;
    const int w = tid >> 6, lane = tid & 63, cc = lane & 15, qq = lane >> 4;

    const f32x4 zf = {0.f, 0.f, 0.f, 0.f};
    f32x4 acc[4][4];
#pragma unroll
    for (int mi = 0; mi < 4; mi++) for (int ji = 0; ji < 4; ji++) acc[mi][ji] = zf;

    for (int kc = 0; kc < 16; kc++) {
        __syncthreads();
        // A tile: 64 H-rows x 32 k (4 KB)
        dma16(H + (size_t)(hrow0 + (tid >> 2)) * 512 + kc * 32 + (tid & 3) * 8, Ash + tid * 8);
        // B tile: 256 n x 32 k (16 KB)
        const unsigned short* bs = (const unsigned short*)W2f + (size_t)kc * 8192;
#pragma unroll
        for (int i = 0; i < 4; i++)
            dma16(bs + i * 2048 + tid * 8, Bsh + i * 2048 + tid * 8);
        __syncthreads();
        bf16x8 af[4];
#pragma unroll
        for (int mi = 0; mi < 4; mi++)
            af[mi] = *(const bf16x8*)((const bf16_t*)Ash + (mi * 16 + cc) * 32 + qq * 8);
#pragma unroll
        for (int ji = 0; ji < 4; ji++) {
            bf16x8 bv = *(const bf16x8*)((const bf16_t*)Bsh + (w * 64 + ji * 16 + cc) * 32 + qq * 8);
#pragma unroll
            for (int mi = 0; mi < 4; mi++)
                acc[mi][ji] = __builtin_amdgcn_mfma_f32_16x16x32_bf16(af[mi], bv, acc[mi][ji], 0, 0, 0);
        }
    }
    __syncthreads();

    // residual staging -> Rf[64][260] fp32 (reuses dead A/B LDS)
    {
        int rr = tid >> 2, q4 = tid & 3;
        int lr = list[base + min(rr, act - 1)];
        int nd = lvl_idx[lr];
        int c0 = lch[nd], c1 = rch[nd], c2 = tern ? tch[nd] : c0;
        int chs[3] = {c0, c1, c2};
        const void* sp[3]; int sf[3];
#pragma unroll
        for (int s = 0; s < 3; s++) {
            int iv = inv[chs[s]];
            if (iv >= 0) { sp[s] = ne2 + (size_t)iv * 256; sf[s] = 0; }
            else if (isbf) { sp[s] = (const bf16_t*)ct + (size_t)cid[chs[s]] * 256; sf[s] = 0; }
            else { sp[s] = (const float*)ct + (size_t)cid[chs[s]] * 256; sf[s] = 1; }
        }
        int nch = tern ? 3 : 2;
        float scale = tern ? (1.0f / 3.0f) : 1.0f;
        for (int i = 0; i < 8; i++) {
            int colq = q4 * 64 + i * 8;
            float s[8] = {0, 0, 0, 0, 0, 0, 0, 0};
            for (int sI = 0; sI < nch; sI++) {
                if (!sf[sI]) {
                    bf16x8 v = *(const bf16x8*)((const bf16_t*)sp[sI] + colq);
                    for (int z = 0; z < 8; z++) s[z] += (float)v[z];
                } else {
                    const float* fp2 = (const float*)sp[sI] + colq;
                    f32x4 a = *(const f32x4*)fp2, b = *(const f32x4*)(fp2 + 4);
                    for (int z = 0; z < 4; z++) { s[z] += a[z]; s[z + 4] += b[z]; }
                }
            }
            f32x4 o0, o1;
            for (int z = 0; z < 4; z++) { o0[z] = s[z] * scale; o1[z] = s[z + 4] * scale; }
            *(f32x4*)(Rf + rr * 260 + colq) = o0;
            *(f32x4*)(Rf + rr * 260 + colq + 4) = o1;
        }
    }
    __syncthreads();

    // x = acc + b2 + R ; LayerNorm
    float b2f[4], gf[4], btf[4];
#pragma unroll
    for (int ji = 0; ji < 4; ji++) {
        int col = w * 64 + ji * 16 + cc;
        b2f[ji] = ldparam(b2, col, isbf);
        gf[ji] = ldparam(gma, col, isbf);
        btf[ji] = ldparam(bta, col, isbf);
    }
#pragma unroll
    for (int mi = 0; mi < 4; mi++) for (int r = 0; r < 4; r++) {
        int row = mi * 16 + qq * 4 + r;
        float ps = 0.f, pq = 0.f;
#pragma unroll
        for (int ji = 0; ji < 4; ji++) {
            int col = w * 64 + ji * 16 + cc;
            float x = acc[mi][ji][r] + b2f[ji] + Rf[row * 260 + col];
            acc[mi][ji][r] = x;
            ps += x; pq += x * x;
        }
        for (int d = 1; d < 16; d <<= 1) {
            ps += __shfl_xor(ps, d, 64);
            pq += __shfl_xor(pq, d, 64);
        }
        if (cc == 0) { partS[w * 64 + row] = ps; partQ[w * 64 + row] = pq; }
    }
    __syncthreads();
    if (tid < 64) {
        float s  = partS[tid] + partS[64 + tid] + partS[128 + tid] + partS[192 + tid];
        float sq = partQ[tid] + partQ[64 + tid] + partQ[128 + tid] + partQ[192 + tid];
        float mu = s * (1.0f / 256.0f);
        float var = sq * (1.0f / 256.0f) - mu * mu;
        muA[tid] = mu;
        rsA[tid] = rsqrtf(fmaxf(var, 0.0f) + 1e-5f);
    }
    __syncthreads();

#pragma unroll
    for (int mi = 0; mi < 4; mi++) for (int r = 0; r < 4; r++) {
        int row = mi * 16 + qq * 4 + r;
        if (row >= act) continue;
        float mu = muA[row], rs = rsA[row];
        int lr2 = list[base + row];
#pragma unroll
        for (int ji = 0; ji < 4; ji++) {
            int col = w * 64 + ji * 16 + cc;
            float y = (acc[mi][ji][r] - mu) * rs * gf[ji] + btf[ji];
            if (out) {
                if (isbf) ((bf16_t*)out)[(size_t)lr2 * 256 + col] = (bf16_t)y;
                else      ((float*)out)[(size_t)lr2 * 256 + col] = y;
            } else {
                ne2[(size_t)(slotBase + lr2) * 256 + col] = (bf16_t)y;
            }
        }
    }
}

extern "C" void kernel_launch(void* const* d_in, const int* in_sizes, int n_in,
                              void* d_out, int out_size, void* d_ws, size_t ws_size,
                              hipStream_t stream) {
    const int* cid    = (const int*)d_in[0];
    const int* opids  = (const int*)d_in[1];
    const int* lch    = (const int*)d_in[2];
    const int* rch    = (const int*)d_in[3];
    const int* tch    = (const int*)d_in[4];
    const int* lvl2   = (const int*)d_in[5];
    const int* lvl1   = (const int*)d_in[6];
    const int* lvl0   = (const int*)d_in[7];
    const void* comp_table = d_in[8];
    const void* op_table   = d_in[9];
    const void* W1b = d_in[10];
    const void* b1b = d_in[11];
    const void* W2b = d_in[12];
    const void* b2b = d_in[13];
    const void* W1t = d_in[14];
    const void* b1t = d_in[15];
    const void* W2t = d_in[16];
    const void* b2t = d_in[17];
    const void* gma = d_in[18];
    const void* bta = d_in[19];

    char* wsp = (char*)d_ws;
    bf16_t* ne2  = (bf16_t*)wsp;                 size_t off = 12582912; // 24576*256*2
    bf16_t* opb  = (bf16_t*)(wsp + off);         off += 8192;
    bf16_t* W1tf = (bf16_t*)(wsp + off);         off += 1048576;        // [32][512][32]
    bf16_t* W1bf = (bf16_t*)(wsp + off);         off += 786432;         // [24][512][32]
    bf16_t* W2tf = (bf16_t*)(wsp + off);         off += 262144;         // [16][256][32]
    bf16_t* W2bf = (bf16_t*)(wsp + off);         off += 262144;
    int* inv   = (int*)(wsp + off);              off += 262144;
    int* lists = (int*)(wsp + off);              off += 229376;
    int* cnts  = (int*)(wsp + off);              off += 64;
    bf16_t* H  = (bf16_t*)(wsp + off);           off += 8519680;        // 8320*512*2 -> total ~24.0 MB
    int* flag  = cnts + 8;

    hipMemsetAsync(cnts, 0, 64, stream);
    hipMemsetAsync(inv, 0xFF, 262144, stream);
    detect_dtype<<<1, 64, 0, stream>>>((const unsigned short*)comp_table, flag);
    scan_rows<<<112, 256, 0, stream>>>(lvl2, lvl1, lvl0, tch, lists, cnts, inv);
    pack_all<<<4624, 256, 0, stream>>>(W1t, W1b, W2t, W2b, op_table,
                                       W1tf, W1bf, W2tf, W2bf, opb, flag);

    // level 2 (slot 0): two 65-block chunks
    for (int c = 0; c < 2; c++) {
        gemm1<<<260, 256, 0, stream>>>(lists + 0, lists + 16384, cnts + 0, lvl2,
            opids, lch, rch, tch, ne2, opb, comp_table, cid, inv, flag,
            W1tf, b1t, W1bf, b1b, H, c);
        gemm2<<<130, 256, 0, stream>>>(lists + 0, lists + 16384, cnts + 0, lvl2,
            lch, rch, tch, ne2, comp_table, cid, inv, flag,
            W2tf, b2t, W2bf, b2b, gma, bta, H, c, 0, nullptr);
    }
    // level 1 (slot 1): one chunk
    gemm1<<<260, 256, 0, stream>>>(lists + 32768, lists + 40960, cnts + 2, lvl1,
        opids, lch, rch, tch, ne2, opb, comp_table, cid, inv, flag,
        W1tf, b1t, W1bf, b1b, H, 0);
    gemm2<<<130, 256, 0, stream>>>(lists + 32768, lists + 40960, cnts + 2, lvl1,
        lch, rch, tch, ne2, comp_table, cid, inv, flag,
        W2tf, b2t, W2bf, b2b, gma, bta, H, 0, 16384, nullptr);
    // level 0 (slot 2): one chunk -> d_out
    gemm1<<<260, 256, 0, stream>>>(lists + 49152, lists + 53248, cnts + 4, lvl0,
        opids, lch, rch, tch, ne2, opb, comp_table, cid, inv, flag,
        W1tf, b1t, W1bf, b1b, H, 0);
    gemm2<<<130, 256, 0, stream>>>(lists + 49152, lists + 53248, cnts + 4, lvl0,
        lch, rch, tch, ne2, comp_table, cid, inv, flag,
        W2tf, b2t, W2bf, b2b, gma, bta, H, 0, 0, d_out);
}

// Round 7
// 297.813 us; speedup vs baseline: 1.2740x; 1.2740x over previous
//
#include <hip/hip_runtime.h>

typedef __bf16 bf16_t;
typedef __attribute__((ext_vector_type(8))) __bf16 bf16x8;
typedef __attribute__((ext_vector_type(4))) float f32x4;
typedef __attribute__((ext_vector_type(8))) unsigned short u16x8;
typedef __attribute__((ext_vector_type(4))) unsigned short u16x4;

// async global->LDS DMA, 16B per lane; LDS dst linear in lane (base + lane*16)
__device__ __forceinline__ void dma16(const void* g, void* l) {
    __builtin_amdgcn_global_load_lds(
        reinterpret_cast<const unsigned int __attribute__((address_space(1)))*>(
            reinterpret_cast<unsigned long long>(g)),
        reinterpret_cast<unsigned int __attribute__((address_space(3)))*>(
            (unsigned int)reinterpret_cast<unsigned long long>(l)),
        16, 0, 0);
}

__device__ __forceinline__ float ldparam(const void* p, int i, int isbf) {
    return isbf ? (float)((const bf16_t*)p)[i] : ((const float*)p)[i];
}

// ---------------- dtype detect: 1 = bf16 inputs, 0 = fp32 inputs
__global__ void detect_dtype(const unsigned short* __restrict__ ct, int* __restrict__ flag) {
    if (threadIdx.x == 0 && blockIdx.x == 0) {
        int ok = 1;
        for (int i = 0; i < 16; i++) {
            int e = (ct[256 + i] >> 7) & 0xFF;
            ok &= (e >= 80 && e <= 126) ? 1 : 0;
        }
        *flag = ok;
    }
}

// ---------------- scan: wave-aggregated partition (1 atomic per wave per bucket)
__global__ void scan_rows(const int* __restrict__ lvl2, const int* __restrict__ lvl1,
                          const int* __restrict__ lvl0, const int* __restrict__ third,
                          int* __restrict__ lists, int* __restrict__ cnts, int* __restrict__ inv) {
    int r = blockIdx.x * 256 + threadIdx.x;   // grid covers exactly 28672
    int slot, lr, base_t, base_b;
    const int* lvl;
    if (r < 16384)      { slot = 0; lr = r;         lvl = lvl2; base_t = 0;     base_b = 16384; }
    else if (r < 24576) { slot = 1; lr = r - 16384; lvl = lvl1; base_t = 32768; base_b = 40960; }
    else                { slot = 2; lr = r - 24576; lvl = lvl0; base_t = 49152; base_b = 53248; }
    int node = lvl[lr];
    int tern = third[node] >= 0 ? 1 : 0;
    if (slot == 0)      inv[node] = lr;
    else if (slot == 1) inv[node] = 16384 + lr;

    unsigned long long bt = __ballot(tern);
    unsigned long long bb = __ballot(!tern);
    int lane = threadIdx.x & 63;
    unsigned long long ltm = (1ull << lane) - 1ull;
    int post = __popcll(bt & ltm), posb = __popcll(bb & ltm);
    int baseT = 0, baseB = 0;
    if (lane == 0) {
        baseT = atomicAdd(&cnts[slot * 2 + 1], __popcll(bt));
        baseB = atomicAdd(&cnts[slot * 2 + 0], __popcll(bb));
    }
    baseT = __shfl(baseT, 0, 64);
    baseB = __shfl(baseB, 0, 64);
    lists[tern ? (base_t + baseT + post) : (base_b + baseB + posb)] = lr;
}

// ---------------- pack weights into MFMA-frag-linear order [kc][jt][lane][8]
__device__ __forceinline__ void packfrag(const void* __restrict__ src, bf16_t* __restrict__ dst,
                                         int k, int n, int koff, int Nshift, int isbf) {
    int si = ((k + koff) << Nshift) + n;
    bf16_t v = isbf ? ((const bf16_t*)src)[si] : (bf16_t)((const float*)src)[si];
    int kc = k >> 5, lane = (((k >> 3) & 3) << 4) | (n & 15), j = k & 7, jt = n >> 4;
    int NT = 1 << (Nshift - 4);
    dst[((((size_t)kc * NT + jt) * 64) + lane) * 8 + j] = v;
}

__global__ void pack_all(const void* __restrict__ W1t, const void* __restrict__ W1b,
                         const void* __restrict__ W2t, const void* __restrict__ W2b,
                         const void* __restrict__ ct,
                         bf16_t* __restrict__ W1tf, bf16_t* __restrict__ W1bf,
                         bf16_t* __restrict__ W2tf, bf16_t* __restrict__ W2bf,
                         bf16_t* __restrict__ ctb, const int* __restrict__ flagp) {
    int e = blockIdx.x * 256 + threadIdx.x;
    int isbf = *flagp;
    if (e < 393216)       packfrag(W1t, W1tf, e >> 9, e & 511, 256, 9, isbf);           // 768x512
    else if (e < 655360)  { int e2 = e - 393216; packfrag(W1b, W1bf, e2 >> 9, e2 & 511, 256, 9, isbf); } // 512x512
    else if (e < 786432)  { int e2 = e - 655360; packfrag(W2t, W2tf, e2 >> 8, e2 & 255, 0, 8, isbf); }   // 512x256
    else if (e < 917504)  { int e2 = e - 786432; packfrag(W2b, W2bf, e2 >> 8, e2 & 255, 0, 8, isbf); }
    else if (e < 1429504) {
        int i = e - 917504;   // 2000*256 comp_table -> bf16
        ctb[i] = isbf ? ((const bf16_t*)ct)[i] : (bf16_t)((const float*)ct)[i];
    }
}

// ---------------- opbias[type][16][512] = op_table @ W1[0:256,:] + b1  (exact fp32)
__global__ void opbias_k(const void* __restrict__ op,
                         const void* __restrict__ W1t, const void* __restrict__ W1b,
                         const void* __restrict__ b1t, const void* __restrict__ b1b,
                         float* __restrict__ obt, float* __restrict__ obb,
                         const int* __restrict__ flagp) {
    __shared__ float opr[256];
    int b = blockIdx.x, isbf = *flagp;
    int typ = b >> 4, o = b & 15;
    const void* W = typ ? W1t : W1b;
    const void* bb = typ ? b1t : b1b;
    float* ob = typ ? obt : obb;
    opr[threadIdx.x] = ldparam(op, o * 256 + threadIdx.x, isbf);
    __syncthreads();
    int n0 = threadIdx.x, n1 = threadIdx.x + 256;
    float a0 = 0.f, a1 = 0.f;
    for (int k = 0; k < 256; k++) {
        float ov = opr[k];
        a0 += ov * ldparam(W, k * 512 + n0, isbf);
        a1 += ov * ldparam(W, k * 512 + n1, isbf);
    }
    ob[o * 512 + n0] = a0 + ldparam(bb, n0, isbf);
    ob[o * 512 + n1] = a1 + ldparam(bb, n1, isbf);
}

__device__ __forceinline__ void load8f(const bf16_t* ne2, const void* ct, int isbf,
                                       int invn, int cidn, int q, float* o) {
    if (invn >= 0) {
        bf16x8 v = *(const bf16x8*)(ne2 + (size_t)invn * 256 + q);
        for (int z = 0; z < 8; z++) o[z] = (float)v[z];
    } else if (isbf) {
        bf16x8 v = *(const bf16x8*)((const bf16_t*)ct + (size_t)cidn * 256 + q);
        for (int z = 0; z < 8; z++) o[z] = (float)v[z];
    } else {
        const float* fp = (const float*)ct + (size_t)cidn * 256 + q;
        f32x4 a = *(const f32x4*)fp, b = *(const f32x4*)(fp + 4);
        for (int z = 0; z < 4; z++) { o[z] = a[z]; o[z + 4] = b[z]; }
    }
}

// ---------------- fused level kernel v3: op-folded, frag-linear DMA staging
__global__ __launch_bounds__(256, 2) void fused_level(
    const int* __restrict__ list_t, const int* __restrict__ list_b,
    const int* __restrict__ cntpair, const int* __restrict__ lvl_idx,
    const int* __restrict__ op_ids, const int* __restrict__ lch,
    const int* __restrict__ rch, const int* __restrict__ tch,
    bf16_t* __restrict__ ne2, const bf16_t* __restrict__ ctb,
    const void* __restrict__ ct, const int* __restrict__ cid,
    const int* __restrict__ inv, const int* __restrict__ flagp,
    const bf16_t* __restrict__ W1tf, const bf16_t* __restrict__ W1bf,
    const bf16_t* __restrict__ W2tf, const bf16_t* __restrict__ W2bf,
    const float* __restrict__ obt, const float* __restrict__ obb,
    const void* __restrict__ b2t, const void* __restrict__ b2b,
    const void* __restrict__ gma, const void* __restrict__ bta,
    int slotBase, void* __restrict__ out)
{
    __shared__ __align__(16) unsigned short Bsh[16384];   // 32 KB weight slab (frag-linear)
    __shared__ __align__(16) unsigned short Ash[1280];    // A [32][40]
    __shared__ __align__(16) unsigned short Hb[16640];    // H [32][520] | Rf float[32][260]
    __shared__ float scr[320];
    __shared__ int opRowL[32];

    const int tid = threadIdx.x;
    const int w = tid >> 6, lane = tid & 63, cc = lane & 15, qq = lane >> 4;
    const int cnt_t = cntpair[1], cnt_b = cntpair[0];
    const int blocks_t = (cnt_t + 31) >> 5;
    int tern, base, cnt, K1c;
    const int* list;
    const bf16_t *W1f, *W2f;
    const float* obp;
    const void* b2;
    if ((int)blockIdx.x < blocks_t) {
        tern = 1; list = list_t; base = blockIdx.x * 32; cnt = cnt_t;
        W1f = W1tf; W2f = W2tf; obp = obt; b2 = b2t; K1c = 24;
    } else {
        tern = 0; list = list_b; base = (blockIdx.x - blocks_t) * 32; cnt = cnt_b;
        if (base >= cnt) return;
        W1f = W1bf; W2f = W2bf; obp = obb; b2 = b2b; K1c = 16;
    }
    const int act = min(32, cnt - base);
    const int isbf = *flagp;

    if (tid < 32) opRowL[tid] = op_ids[lvl_idx[list[base + min(tid, act - 1)]]];

    // staging identity: thread covers row ms, col-group gs (4 shorts)
    const int ms = tid >> 3, gs = tid & 7;
    int sInv[3], sCid[3];
    const bf16_t* srcPtr[3];
    {
        int lrS = list[base + min(ms, act - 1)];
        int ndS = lvl_idx[lrS];
        int sn[3] = {lch[ndS], rch[ndS], tern ? tch[ndS] : lch[ndS]};
#pragma unroll
        for (int s = 0; s < 3; s++) {
            sInv[s] = inv[sn[s]];
            sCid[s] = sInv[s] < 0 ? cid[sn[s]] : 0;
            srcPtr[s] = sInv[s] >= 0 ? ne2 + (size_t)sInv[s] * 256 : ctb + (size_t)sCid[s] * 256;
        }
    }

    const f32x4 zf = {0.f, 0.f, 0.f, 0.f};
    f32x4 acc1[2][8];
#pragma unroll
    for (int m = 0; m < 2; m++) for (int j = 0; j < 8; j++) acc1[m][j] = zf;

    // ---------- GEMM1: [32 x K1] @ W1[children] -> acc1   (BK=32)
    for (int kc = 0; kc < K1c; kc++) {
        __syncthreads();
        { // A stage: children only (all bf16), pure 8-B copy
            int colg = kc * 32 + gs * 4;
            int p = colg >> 8, po = colg & 255;
            *(u16x4*)(Ash + ms * 40 + gs * 4) = *(const u16x4*)(srcPtr[p] + po);
            // B slab DMA: 32 KB frag-linear
            const unsigned short* bs = (const unsigned short*)W1f + (size_t)kc * 16384;
#pragma unroll
            for (int i = 0; i < 8; i++)
                dma16(bs + i * 2048 + tid * 8, Bsh + i * 2048 + tid * 8);
        }
        __syncthreads();
        bf16x8 af[2];
        af[0] = *(const bf16x8*)((const bf16_t*)Ash + cc * 40 + qq * 8);
        af[1] = *(const bf16x8*)((const bf16_t*)Ash + (16 + cc) * 40 + qq * 8);
#pragma unroll
        for (int j = 0; j < 8; j++) {
            bf16x8 bv = *(const bf16x8*)((const bf16_t*)Bsh + (((w + 4 * j) * 64) + lane) * 8);
            acc1[0][j] = __builtin_amdgcn_mfma_f32_16x16x32_bf16(af[0], bv, acc1[0][j], 0, 0, 0);
            acc1[1][j] = __builtin_amdgcn_mfma_f32_16x16x32_bf16(af[1], bv, acc1[1][j], 0, 0, 0);
        }
    }
    __syncthreads();

    // ---------- opbias + exact GELU -> H in LDS [32][520]
    {
        bf16_t* Hl = (bf16_t*)Hb;
#pragma unroll
        for (int m = 0; m < 2; m++) for (int j = 0; j < 8; j++) {
            int col = (w + 4 * j) * 16 + cc;
#pragma unroll
            for (int r = 0; r < 4; r++) {
                int row = m * 16 + qq * 4 + r;
                float v = acc1[m][j][r] + obp[opRowL[row] * 512 + col];
                float h = 0.5f * v * (1.0f + erff(v * 0.70710678118654752f));
                Hl[row * 520 + col] = (bf16_t)h;
            }
        }
    }

    // ---------- GEMM2: [32 x 512] @ W2 -> acc2   (BK=64, 8 iters)
    f32x4 acc2[2][4];
#pragma unroll
    for (int m = 0; m < 2; m++) for (int j = 0; j < 4; j++) acc2[m][j] = zf;
    for (int kc2 = 0; kc2 < 8; kc2++) {
        __syncthreads();
        const unsigned short* bs = (const unsigned short*)W2f + (size_t)kc2 * 16384;
#pragma unroll
        for (int i = 0; i < 8; i++)
            dma16(bs + i * 2048 + tid * 8, Bsh + i * 2048 + tid * 8);
        __syncthreads();
#pragma unroll
        for (int s = 0; s < 2; s++) {
            int kk = kc2 * 2 + s;
            bf16x8 af[2];
            af[0] = *(const bf16x8*)((const bf16_t*)Hb + cc * 520 + kk * 32 + qq * 8);
            af[1] = *(const bf16x8*)((const bf16_t*)Hb + (16 + cc) * 520 + kk * 32 + qq * 8);
#pragma unroll
            for (int j = 0; j < 4; j++) {
                bf16x8 bv = *(const bf16x8*)((const bf16_t*)Bsh + s * 8192 + (((w + 4 * j) * 64) + lane) * 8);
                acc2[0][j] = __builtin_amdgcn_mfma_f32_16x16x32_bf16(af[0], bv, acc2[0][j], 0, 0, 0);
                acc2[1][j] = __builtin_amdgcn_mfma_f32_16x16x32_bf16(af[1], bv, acc2[1][j], 0, 0, 0);
            }
        }
    }
    __syncthreads();

    // ---------- residual gather -> Hb as float[32][260]
    {
        float* Rf = (float*)Hb;
        int colb = gs * 32;
        for (int i = 0; i < 4; i++) {
            int q = colb + i * 8;
            float lv[8], rv[8], tv[8];
            load8f(ne2, ct, isbf, sInv[0], sCid[0], q, lv);
            load8f(ne2, ct, isbf, sInv[1], sCid[1], q, rv);
            if (tern) load8f(ne2, ct, isbf, sInv[2], sCid[2], q, tv);
            f32x4 s0, s1;
            if (tern) {
                for (int z = 0; z < 4; z++) {
                    s0[z] = (lv[z] + rv[z] + tv[z]) * (1.0f / 3.0f);
                    s1[z] = (lv[z + 4] + rv[z + 4] + tv[z + 4]) * (1.0f / 3.0f);
                }
            } else {
                for (int z = 0; z < 4; z++) {
                    s0[z] = lv[z] + rv[z];
                    s1[z] = lv[z + 4] + rv[z + 4];
                }
            }
            *(f32x4*)(Rf + ms * 260 + q) = s0;
            *(f32x4*)(Rf + ms * 260 + q + 4) = s1;
        }
    }
    __syncthreads();

    // ---------- x = acc2 + b2 + R ; LayerNorm
    float b2f[4], gf[4], btf[4];
#pragma unroll
    for (int j = 0; j < 4; j++) {
        int col = (w + 4 * j) * 16 + cc;
        b2f[j] = ldparam(b2, col, isbf);
        gf[j] = ldparam(gma, col, isbf);
        btf[j] = ldparam(bta, col, isbf);
    }
    float* partS = scr;
    float* partQ = scr + 128;
    float* muA   = scr + 256;
    float* rsA   = scr + 288;
    const float* Rf = (const float*)Hb;

#pragma unroll
    for (int m = 0; m < 2; m++) for (int r = 0; r < 4; r++) {
        int row = m * 16 + qq * 4 + r;
        float ps = 0.f, pq = 0.f;
#pragma unroll
        for (int j = 0; j < 4; j++) {
            int col = (w + 4 * j) * 16 + cc;
            float x = acc2[m][j][r] + b2f[j] + Rf[row * 260 + col];
            acc2[m][j][r] = x;
            ps += x; pq += x * x;
        }
        for (int d = 1; d < 16; d <<= 1) {
            ps += __shfl_xor(ps, d, 64);
            pq += __shfl_xor(pq, d, 64);
        }
        if (cc == 0) { partS[w * 32 + row] = ps; partQ[w * 32 + row] = pq; }
    }
    __syncthreads();
    if (tid < 32) {
        float s  = partS[tid] + partS[32 + tid] + partS[64 + tid] + partS[96 + tid];
        float sq = partQ[tid] + partQ[32 + tid] + partQ[64 + tid] + partQ[96 + tid];
        float mu = s * (1.0f / 256.0f);
        float var = sq * (1.0f / 256.0f) - mu * mu;
        muA[tid] = mu;
        rsA[tid] = rsqrtf(fmaxf(var, 0.0f) + 1e-5f);
    }
    __syncthreads();

#pragma unroll
    for (int m = 0; m < 2; m++) for (int r = 0; r < 4; r++) {
        int row = m * 16 + qq * 4 + r;
        if (row >= act) continue;
        float mu = muA[row], rs = rsA[row];
        int lr2 = list[base + row];
#pragma unroll
        for (int j = 0; j < 4; j++) {
            int col = (w + 4 * j) * 16 + cc;
            float y = (acc2[m][j][r] - mu) * rs * gf[j] + btf[j];
            if (out) {
                if (isbf) ((bf16_t*)out)[(size_t)lr2 * 256 + col] = (bf16_t)y;
                else      ((float*)out)[(size_t)lr2 * 256 + col] = y;
            } else {
                ne2[(size_t)(slotBase + lr2) * 256 + col] = (bf16_t)y;
            }
        }
    }
}

extern "C" void kernel_launch(void* const* d_in, const int* in_sizes, int n_in,
                              void* d_out, int out_size, void* d_ws, size_t ws_size,
                              hipStream_t stream) {
    const int* cid    = (const int*)d_in[0];
    const int* opids  = (const int*)d_in[1];
    const int* lch    = (const int*)d_in[2];
    const int* rch    = (const int*)d_in[3];
    const int* tch    = (const int*)d_in[4];
    const int* lvl2   = (const int*)d_in[5];
    const int* lvl1   = (const int*)d_in[6];
    const int* lvl0   = (const int*)d_in[7];
    const void* comp_table = d_in[8];
    const void* op_table   = d_in[9];
    const void* W1b = d_in[10];
    const void* b1b = d_in[11];
    const void* W2b = d_in[12];
    const void* b2b = d_in[13];
    const void* W1t = d_in[14];
    const void* b1t = d_in[15];
    const void* W2t = d_in[16];
    const void* b2t = d_in[17];
    const void* gma = d_in[18];
    const void* bta = d_in[19];

    char* wsp = (char*)d_ws;
    bf16_t* ne2  = (bf16_t*)wsp;                 size_t off = 12582912; // 24576*256*2
    bf16_t* ctb  = (bf16_t*)(wsp + off);         off += 1024000;        // 2000*256*2
    bf16_t* W1tf = (bf16_t*)(wsp + off);         off += 786432;         // 768*512*2 (children rows)
    bf16_t* W1bf = (bf16_t*)(wsp + off);         off += 524288;         // 512*512*2
    bf16_t* W2tf = (bf16_t*)(wsp + off);         off += 262144;         // 512*256*2
    bf16_t* W2bf = (bf16_t*)(wsp + off);         off += 262144;
    float* obt   = (float*)(wsp + off);          off += 32768;          // 16*512*4
    float* obb   = (float*)(wsp + off);          off += 32768;
    int* inv   = (int*)(wsp + off);              off += 262144;
    int* lists = (int*)(wsp + off);              off += 229376;
    int* cnts  = (int*)(wsp + off);              off += 64;             // ~16.0 MB
    int* flag  = cnts + 8;

    hipMemsetAsync(cnts, 0, 64, stream);
    hipMemsetAsync(inv, 0xFF, 262144, stream);
    detect_dtype<<<1, 64, 0, stream>>>((const unsigned short*)comp_table, flag);
    scan_rows<<<112, 256, 0, stream>>>(lvl2, lvl1, lvl0, tch, lists, cnts, inv);
    pack_all<<<5584, 256, 0, stream>>>(W1t, W1b, W2t, W2b, comp_table,
                                       W1tf, W1bf, W2tf, W2bf, ctb, flag);
    opbias_k<<<32, 256, 0, stream>>>(op_table, W1t, W1b, b1t, b1b, obt, obb, flag);

    // level 2: t @0 / b @16384, cnts slot 0 -> slots base 0
    fused_level<<<513, 256, 0, stream>>>(lists + 0, lists + 16384, cnts + 0, lvl2,
        opids, lch, rch, tch, ne2, ctb, comp_table, cid, inv, flag,
        W1tf, W1bf, W2tf, W2bf, obt, obb, b2t, b2b, gma, bta, 0, nullptr);
    // level 1: t @32768 / b @40960, cnts slot 1 -> slots base 16384
    fused_level<<<257, 256, 0, stream>>>(lists + 32768, lists + 40960, cnts + 2, lvl1,
        opids, lch, rch, tch, ne2, ctb, comp_table, cid, inv, flag,
        W1tf, W1bf, W2tf, W2bf, obt, obb, b2t, b2b, gma, bta, 16384, nullptr);
    // level 0: t @49152 / b @53248, cnts slot 2 -> d_out
    fused_level<<<129, 256, 0, stream>>>(lists + 49152, lists + 53248, cnts + 4, lvl0,
        opids, lch, rch, tch, ne2, ctb, comp_table, cid, inv, flag,
        W1tf, W1bf, W2tf, W2bf, obt, obb, b2t, b2b, gma, bta, 0, d_out);
}